// Round 4
// baseline (117.257 us; speedup 1.0000x reference)
//
#include <hip/hip_runtime.h>

// GauntTensorProductFixedParity — R10: persistent 2-chunk pipeline.
//
// Same verified MFMA chain as R9 (zero-transpose, fused):
//   stage 1 (16x16x32): c^T[s,row]  = sum_d W[d,s]·in[row,d]     (A=W, B=in)
//   stage 2 (16x16x16): G[p,row]    = sum_s Y[p,s]·c^T[s,row]    (A=Yf, B=c-chain)
//   H = G1 ⊙ G2; GEMM2 (16x16x16): out[s,row] += sum_p Yw^T[s,p]·H[p,row]
//
// R10 change: grid 256 (1 block/CU), each block processes TWO 256-row chunks
// straight-line with cross-chunk prefetch: chunk-1's 32 global loads/wave are
// issued right after chunk-0's cvt frees the f32 staging registers, so
// chunk-1's HBM delivery overlaps chunk-0's entire MFMA chain. Removes the
// per-block relaunch + burst-latency bubble that R6-R9 paid every 256 rows,
// and halves the Y/Yw/W staging + barrier cost per row.
// VGPR ~330 -> __launch_bounds__(256,1) (1 block/CU, intended).
//
// Verified lane mappings (R7/R8/R9 lineage, all harness-passed):
//   A/B-frag K=32: (idx = lane&15, k = quad*8+j)
//   A/B-frag K=16: (idx = lane&15, k = quad*4+i)
//   C/D:           (n = lane&15,   m = quad*4+i)
//
// LDS: Yf [pt9][st2][64][4]h = 9216B | Ywf [st2][pt9][64][4]h = 9216B.

typedef _Float16 f16x8 __attribute__((ext_vector_type(8)));
typedef _Float16 f16x4 __attribute__((ext_vector_type(4)));
typedef float f32x4 __attribute__((ext_vector_type(4)));
typedef float f32x4u __attribute__((ext_vector_type(4), aligned(4)));

namespace {
constexpr int kD = 64, kS = 25, kP = 132;
constexpr int kBlock = 256, kM = 256;        // rows per chunk (4 waves x 64 rows)
constexpr int kYfOff = 0;                    // [9][2][64][4] halfs = 4608
constexpr int kYwOff = 4608;                 // [2][9][64][4] halfs = 4608
constexpr int kLdsHalfs = 9216;              // 18432 B
}

__device__ __forceinline__ f16x4 ld4(const _Float16* p) {
    return *reinterpret_cast<const f16x4*>(p);
}
__device__ __forceinline__ f16x8 cvt8h(f32x4 u, f32x4 v) {
    f16x8 r;
    r[0] = (_Float16)u[0]; r[1] = (_Float16)u[1];
    r[2] = (_Float16)u[2]; r[3] = (_Float16)u[3];
    r[4] = (_Float16)v[0]; r[5] = (_Float16)v[1];
    r[6] = (_Float16)v[2]; r[7] = (_Float16)v[3];
    return r;
}

__global__ __launch_bounds__(kBlock, 1) void gaunt_fused10(
    const float* __restrict__ in1, const float* __restrict__ in2,
    const float* __restrict__ W1, const float* __restrict__ W2,
    const float* __restrict__ Y,  const float* __restrict__ Yw,
    float* __restrict__ out)
{
    __shared__ _Float16 lds[kLdsHalfs];
    const int tid  = threadIdx.x;
    const int lane = tid & 63;
    const int w    = __builtin_amdgcn_readfirstlane(tid >> 6);
    const int lo16 = lane & 15, quad = lane >> 4;

    // Two consecutive 256-row chunks per block.
    const long long rowbase = (long long)blockIdx.x * (2 * kM);

    // ---- f32 staging registers (reused across chunks) ----
    f32x4 su1[4][2], sv1[4][2], su2[4][2], sv2[4][2];

    auto issue_loads = [&](long long rb) {
        #pragma unroll
        for (int rt = 0; rt < 4; ++rt) {
            const long long row = rb + (4 * w + rt) * 16 + lo16;
            const float* p1 = in1 + row * kD + quad * 8;
            const float* p2 = in2 + row * kD + quad * 8;
            #pragma unroll
            for (int ks = 0; ks < 2; ++ks) {
                su1[rt][ks] = *reinterpret_cast<const f32x4*>(p1 + ks * 32);
                sv1[rt][ks] = *reinterpret_cast<const f32x4*>(p1 + ks * 32 + 4);
                su2[rt][ks] = *reinterpret_cast<const f32x4*>(p2 + ks * 32);
                sv2[rt][ks] = *reinterpret_cast<const f32x4*>(p2 + ks * 32 + 4);
            }
        }
    };

    // ---- Phase A: issue chunk-0 input burst FIRST ----
    issue_loads(rowbase);

    // ---- Phase B: Y K=16 A-frags -> LDS (overlaps input latency).
    //      Yf(pt,st): A(m = p = pt*16+lo16, k = s = st*16+quad*4+i)
    for (int e = tid; e < 4608; e += kBlock) {
        const int i = e & 3, ln = (e >> 2) & 63, r = e >> 8;  // r 0..17
        const int pt = r >> 1, st = r & 1;
        const int p = pt * 16 + (ln & 15);                    // 0..143
        const int s = st * 16 + ((ln >> 4) & 3) * 4 + i;      // 0..31
        lds[kYfOff + e] = (s < kS && p < kP) ? (_Float16)Y[p * kS + s]
                                             : (_Float16)0.f;
    }
    // ---- Ywt K=16 A-frags -> LDS.  A(m = s = st*16+lo16, k = p = pt*16+quad*4+i)
    for (int e = tid; e < 4608; e += kBlock) {
        const int i = e & 3, ln = (e >> 2) & 63, r = e >> 8;  // r 0..17
        const int pt = r % 9, st = r / 9;
        const int p = pt * 16 + ((ln >> 4) & 3) * 4 + i;      // 0..143
        const int s = st * 16 + (ln & 15);                    // 0..31
        lds[kYwOff + e] = (s < kS && p < kP) ? (_Float16)Yw[p * kS + s]
                                             : (_Float16)0.f;
    }

    // ---- Phase C: W A-frags (K=32) -> registers.  A(m = s, k = d) = W[d][s]
    f16x8 w1f[2][2], w2f[2][2];                   // [st][ks]
    #pragma unroll
    for (int st = 0; st < 2; ++st) {
        const int s = st * 16 + lo16;
        #pragma unroll
        for (int ks = 0; ks < 2; ++ks) {
            f16x8 a, b;
            #pragma unroll
            for (int j = 0; j < 8; ++j) { a[j] = (_Float16)0.f; b[j] = (_Float16)0.f; }
            if (s < kS) {
                const int d0 = ks * 32 + quad * 8;
                #pragma unroll
                for (int j = 0; j < 8; ++j) {
                    a[j] = (_Float16)W1[(d0 + j) * kS + s];
                    b[j] = (_Float16)W2[(d0 + j) * kS + s];
                }
            }
            w1f[st][ks] = a; w2f[st][ks] = b;
        }
    }

    __syncthreads();

    // ---- f16 input B-frags for the chunk being computed ----
    f16x8 b1[4][2], b2[4][2];
    auto cvt_all = [&]() {
        #pragma unroll
        for (int rt = 0; rt < 4; ++rt)
            #pragma unroll
            for (int ks = 0; ks < 2; ++ks) {
                b1[rt][ks] = cvt8h(su1[rt][ks], sv1[rt][ks]);
                b2[rt][ks] = cvt8h(su2[rt][ks], sv2[rt][ks]);
            }
    };

    auto compute_store = [&](long long rb) {
        // ---- Stage 1: c^T = W^T·in^T.  C(n=row=lo16, m=s=quad*4+i) ----
        f16x4 h1c[4][2], h2c[4][2];               // [rt][st] B-frags (n=row, k=s)
        #pragma unroll
        for (int rt = 0; rt < 4; ++rt) {
            #pragma unroll
            for (int st = 0; st < 2; ++st) {
                f32x4 c1 = (f32x4){0.f, 0.f, 0.f, 0.f};
                f32x4 c2 = (f32x4){0.f, 0.f, 0.f, 0.f};
                #pragma unroll
                for (int ks = 0; ks < 2; ++ks) {
                    c1 = __builtin_amdgcn_mfma_f32_16x16x32_f16(w1f[st][ks], b1[rt][ks], c1, 0, 0, 0);
                    c2 = __builtin_amdgcn_mfma_f32_16x16x32_f16(w2f[st][ks], b2[rt][ks], c2, 0, 0, 0);
                }
                f16x4 hc1, hc2;
                #pragma unroll
                for (int i = 0; i < 4; ++i) {
                    hc1[i] = (_Float16)c1[i];
                    hc2[i] = (_Float16)c2[i];
                }
                h1c[rt][st] = hc1; h2c[rt][st] = hc2;
            }
        }

        // ---- Stage 2 + GEMM2 over 9 p-tiles; Y/Yw frags dbuf'd from LDS ----
        f32x4 oacc[4][2];
        #pragma unroll
        for (int rt = 0; rt < 4; ++rt)
            #pragma unroll
            for (int st = 0; st < 2; ++st)
                oacc[rt][st] = (f32x4){0.f, 0.f, 0.f, 0.f};

        f16x4 yfc[2], yw0c, yw1c;
        yfc[0] = ld4(&lds[kYfOff + 0 * 256 + lane * 4]);
        yfc[1] = ld4(&lds[kYfOff + 1 * 256 + lane * 4]);
        yw0c   = ld4(&lds[kYwOff + 0 * 256 + lane * 4]);
        yw1c   = ld4(&lds[kYwOff + 9 * 256 + lane * 4]);

        #pragma unroll 1
        for (int pt = 0; pt < 9; ++pt) {
            f16x4 yfn[2], yw0n, yw1n;
            if (pt < 8) {
                yfn[0] = ld4(&lds[kYfOff + ((pt + 1) * 2 + 0) * 256 + lane * 4]);
                yfn[1] = ld4(&lds[kYfOff + ((pt + 1) * 2 + 1) * 256 + lane * 4]);
                yw0n   = ld4(&lds[kYwOff + (0 * 9 + pt + 1) * 256 + lane * 4]);
                yw1n   = ld4(&lds[kYwOff + (1 * 9 + pt + 1) * 256 + lane * 4]);
            }
            #pragma unroll
            for (int rt = 0; rt < 4; ++rt) {
                const f32x4 z = (f32x4){0.f, 0.f, 0.f, 0.f};
                f32x4 g1 = __builtin_amdgcn_mfma_f32_16x16x16f16(yfc[0], h1c[rt][0], z, 0, 0, 0);
                g1       = __builtin_amdgcn_mfma_f32_16x16x16f16(yfc[1], h1c[rt][1], g1, 0, 0, 0);
                f32x4 g2 = __builtin_amdgcn_mfma_f32_16x16x16f16(yfc[0], h2c[rt][0], z, 0, 0, 0);
                g2       = __builtin_amdgcn_mfma_f32_16x16x16f16(yfc[1], h2c[rt][1], g2, 0, 0, 0);
                f16x4 h;
                h[0] = (_Float16)(g1[0] * g2[0]);
                h[1] = (_Float16)(g1[1] * g2[1]);
                h[2] = (_Float16)(g1[2] * g2[2]);
                h[3] = (_Float16)(g1[3] * g2[3]);
                oacc[rt][0] = __builtin_amdgcn_mfma_f32_16x16x16f16(yw0c, h, oacc[rt][0], 0, 0, 0);
                oacc[rt][1] = __builtin_amdgcn_mfma_f32_16x16x16f16(yw1c, h, oacc[rt][1], 0, 0, 0);
            }
            yfc[0] = yfn[0]; yfc[1] = yfn[1]; yw0c = yw0n; yw1c = yw1n;
        }

        // ---- stores: out^T C-layout (n=row, m=s) -> 16B runs ----
        #pragma unroll
        for (int rt = 0; rt < 4; ++rt) {
            const long long row = rb + (4 * w + rt) * 16 + lo16;
            float* rp = out + row * kS;
            *reinterpret_cast<f32x4u*>(rp + quad * 4) = oacc[rt][0];
            if (quad < 2) {
                *reinterpret_cast<f32x4u*>(rp + 16 + quad * 4) = oacc[rt][1];
            } else if (quad == 2) {
                rp[24] = oacc[rt][1][0];
            }
        }
    };

    // ---- chunk 0: cvt (waits c0 data), then immediately prefetch chunk 1 ----
    cvt_all();
    issue_loads(rowbase + kM);        // c1 HBM delivery overlaps c0 compute
    compute_store(rowbase);

    // ---- chunk 1 ----
    cvt_all();                        // waits c1 data (stores may stay in flight)
    compute_store(rowbase + kM);
}

extern "C" void kernel_launch(void* const* d_in, const int* in_sizes, int n_in,
                              void* d_out, int out_size, void* d_ws, size_t ws_size,
                              hipStream_t stream) {
    const float* in1 = (const float*)d_in[0];   // [N, 64]
    const float* in2 = (const float*)d_in[1];   // [N, 64]
    const float* W1  = (const float*)d_in[2];   // [64, 25]
    const float* W2  = (const float*)d_in[3];   // [64, 25]
    const float* Y   = (const float*)d_in[4];   // [132, 25]
    const float* Yw  = (const float*)d_in[5];   // [132, 25]
    float* out = (float*)d_out;                 // [N, 25]
    (void)d_ws; (void)ws_size;

    const int n_rows = in_sizes[0] / kD;        // 131072
    const int grid = n_rows / (2 * kM);         // 256 persistent blocks, 1/CU
    gaunt_fused10<<<grid, kBlock, 0, stream>>>(in1, in2, W1, W2, Y, Yw, out);
}

// Round 5
// 112.601 us; speedup vs baseline: 1.0413x; 1.0413x over previous
//
#include <hip/hip_runtime.h>

// GauntTensorProductFixedParity — R11: global_load_lds staging + high occupancy.
//
// R10 rocprof: gaunt 40.8 µs @ 1151 GB/s, MfmaUtil 7%, Occupancy 9.5% —
// latency-bound. Fix: (1) input staging via global_load_lds width-16 (queue-
// based MLP, no VGPR landing zones, compiler can't serialize it); (2) 16-B
// slot XOR swizzle on the LDS tile (inverse-swizzled SOURCE address, linear
// LDS dest, swizzled read — both-sides rule) -> conflict-free ds_read_b128;
// (3) kM=64, grid=2048, VGPR<=128 -> 4 blocks/CU = 16 waves/CU TLP;
// (4) Y/Yw/W frag tables precomputed once into ws (pure swizzle kernel),
// hot kernel reads them as L1/L2-hot register frags (26 KB total).
//
// Compute chain = rt=1 specialization of R9's verified pipeline:
//   stage 1 (16x16x32): c^T[s,row]  = sum_d W[d,s]·in[row,d]   (A=Wf, B=in)
//   stage 2 (16x16x16): G[p,row]    = sum_s Y[p,s]·c^T[s,row]  (A=Yf, B=c-chain)
//   H = G1 ⊙ G2 ; GEMM2 (16x16x16): out[s,row] += sum_p Yw^T[s,p]·H[p,row]
// Lane mappings (harness-verified R7-R10):
//   A/B-frag K=32: (idx = lane&15, k = quad*8+j)
//   A/B-frag K=16: (idx = lane&15, k = quad*4+i)
//   C/D:           (n = lane&15,   m = quad*4+i)

typedef _Float16 f16x8 __attribute__((ext_vector_type(8)));
typedef _Float16 f16x4 __attribute__((ext_vector_type(4)));
typedef float f32x4 __attribute__((ext_vector_type(4)));
typedef float f32x4u __attribute__((ext_vector_type(4), aligned(4)));

namespace {
constexpr int kD = 64, kS = 25, kP = 132;
constexpr int kBlock = 256, kM = 64;     // rows per block (4 waves x 16 rows)
// ws layout (halfs):
constexpr int kYfOff = 0;                // Yf  [pt9][st2][64][4] = 4608
constexpr int kYwOff = 4608;             // Ywt [st2][pt9][64][4] = 4608
constexpr int kWfOff = 9216;             // Wf  [op2][st2][ks2][64][8] = 4096
constexpr int kWsHalfs = 13312;          // 26624 B
}

// ---- Precompute: pure-swizzle frag tables (no FMA) ----
__global__ void precompute11(const float* __restrict__ W1,
                             const float* __restrict__ W2,
                             const float* __restrict__ Y,
                             const float* __restrict__ Yw,
                             _Float16* __restrict__ ws) {
    const int e = blockIdx.x * blockDim.x + threadIdx.x;
    if (e < 4608) {
        // Yf(pt,st): A(m = p = pt*16+lo16, k = s = st*16+quad*4+i)
        const int i = e & 3, ln = (e >> 2) & 63, r = e >> 8;   // r 0..17
        const int pt = r >> 1, st = r & 1;
        const int p = pt * 16 + (ln & 15);
        const int s = st * 16 + ((ln >> 4) & 3) * 4 + i;
        ws[kYfOff + e] = (s < kS && p < kP) ? (_Float16)Y[p * kS + s]
                                            : (_Float16)0.f;
    } else if (e < 9216) {
        // Ywt(st,pt): A(m = s = st*16+lo16, k = p = pt*16+quad*4+i)
        const int e2 = e - 4608;
        const int i = e2 & 3, ln = (e2 >> 2) & 63, r = e2 >> 8; // r 0..17
        const int pt = r % 9, st = r / 9;
        const int p = pt * 16 + ((ln >> 4) & 3) * 4 + i;
        const int s = st * 16 + (ln & 15);
        ws[kYwOff + e2] = (s < kS && p < kP) ? (_Float16)Yw[p * kS + s]
                                             : (_Float16)0.f;
    } else if (e < kWsHalfs) {
        // Wf(op,st,ks): A(m = s = st*16+lo16, k = d = ks*32+quad*8+j)
        const int e3 = e - 9216;
        const int j = e3 & 7, ln = (e3 >> 3) & 63, r = e3 >> 9; // r 0..7
        const int ks = r & 1, st = (r >> 1) & 1, op = r >> 2;
        const int s = st * 16 + (ln & 15);
        const int d = ks * 32 + ((ln >> 4) & 3) * 8 + j;
        const float* W = op ? W2 : W1;
        ws[kWfOff + e3] = (s < kS) ? (_Float16)W[d * kS + s] : (_Float16)0.f;
    }
}

__device__ __forceinline__ f16x8 ld8(const _Float16* p) {
    return *reinterpret_cast<const f16x8*>(p);
}
__device__ __forceinline__ f16x4 ld4(const _Float16* p) {
    return *reinterpret_cast<const f16x4*>(p);
}
__device__ __forceinline__ f16x8 cvt8h(f32x4 u, f32x4 v) {
    f16x8 r;
    r[0] = (_Float16)u[0]; r[1] = (_Float16)u[1];
    r[2] = (_Float16)u[2]; r[3] = (_Float16)u[3];
    r[4] = (_Float16)v[0]; r[5] = (_Float16)v[1];
    r[6] = (_Float16)v[2]; r[7] = (_Float16)v[3];
    return r;
}

__global__ __launch_bounds__(kBlock, 4) void gaunt_fused11(
    const float* __restrict__ in1, const float* __restrict__ in2,
    const _Float16* __restrict__ ws, float* __restrict__ out)
{
    // Input tile: [op][row 64][slot 16] of f32x4, 16-B slots XOR-swizzled:
    // logical (r, s) lives at LDS (r, s ^ (r&7)).  32 KB.
    __shared__ f32x4 ldsq[2][kM][16];

    const int tid  = threadIdx.x;
    const int lane = tid & 63;
    const int w    = __builtin_amdgcn_readfirstlane(tid >> 6);
    const int lo16 = lane & 15, quad = lane >> 4;

    const long long rowbase = (long long)blockIdx.x * kM;

    // ---- stage inputs: 32 x global_load_lds(16B), 8 per wave.
    // Instruction t covers rows q*4..q*4+3 of op (1 KB, wave-linear dest).
    // Lane l -> dest slot (l&15) of row q*4+(l>>4); fetch SOURCE slot
    // (l&15)^(r&7) so that LDS(r,t) holds logical slot t^(r&7).
    {
        const int rg = lane >> 4;          // row within 4-row group
        const int sl = lane & 15;          // dest slot
        #pragma unroll
        for (int i = 0; i < 8; ++i) {
            const int t  = w * 8 + i;      // 0..31
            const int op = t >> 4, q = t & 15;
            const int r  = q * 4 + rg;
            const int c16 = sl ^ (r & 7);  // source slot
            const float* src = (op ? in2 : in1) + (rowbase + r) * kD + c16 * 4;
            char* dst = (char*)(&ldsq[0][0][0]) + op * 16384 + q * 1024;
            __builtin_amdgcn_global_load_lds(
                (const __attribute__((address_space(1))) void*)src,
                (__attribute__((address_space(3))) void*)dst,
                16, 0, 0);
        }
    }

    // ---- frag tables from ws (independent of LDS; overlap staging) ----
    const _Float16* wsYf = ws + kYfOff;
    const _Float16* wsYw = ws + kYwOff;
    const _Float16* wsWf = ws + kWfOff;

    f16x8 w1f[2][2], w2f[2][2];            // [st][ks], live whole kernel
    #pragma unroll
    for (int st = 0; st < 2; ++st)
        #pragma unroll
        for (int ks = 0; ks < 2; ++ks) {
            w1f[st][ks] = ld8(&wsWf[((0 * 2 + st) * 2 + ks) * 512 + lane * 8]);
            w2f[st][ks] = ld8(&wsWf[((1 * 2 + st) * 2 + ks) * 512 + lane * 8]);
        }
    f16x4 yfc0 = ld4(&wsYf[0 * 256 + lane * 4]);
    f16x4 yfc1 = ld4(&wsYf[1 * 256 + lane * 4]);
    f16x4 yw0c = ld4(&wsYw[0 * 256 + lane * 4]);
    f16x4 yw1c = ld4(&wsYw[9 * 256 + lane * 4]);

    __syncthreads();                        // drains global_load_lds (vmcnt 0)

    // ---- read input B-frags from swizzled LDS (conflict-free) ----
    const int r  = w * 16 + lo16;           // local row
    const int r7 = lo16 & 7;
    f16x8 b1[2], b2[2];
    #pragma unroll
    for (int ks = 0; ks < 2; ++ks) {
        const int s0 = ks * 8 + quad * 2;   // logical 16-B slot = d0/4
        const f32x4 u = ldsq[0][r][s0 ^ r7];
        const f32x4 v = ldsq[0][r][(s0 + 1) ^ r7];
        b1[ks] = cvt8h(u, v);
    }
    #pragma unroll
    for (int ks = 0; ks < 2; ++ks) {
        const int s0 = ks * 8 + quad * 2;
        const f32x4 u = ldsq[1][r][s0 ^ r7];
        const f32x4 v = ldsq[1][r][(s0 + 1) ^ r7];
        b2[ks] = cvt8h(u, v);
    }

    // ---- Stage 1: c^T = W^T·in^T.  C(n=row=lo16, m=s=quad*4+i) ----
    f16x4 h1c[2], h2c[2];                   // [st] B-frags (n=row, k=s)
    #pragma unroll
    for (int st = 0; st < 2; ++st) {
        f32x4 c1 = (f32x4){0.f, 0.f, 0.f, 0.f};
        f32x4 c2 = (f32x4){0.f, 0.f, 0.f, 0.f};
        #pragma unroll
        for (int ks = 0; ks < 2; ++ks) {
            c1 = __builtin_amdgcn_mfma_f32_16x16x32_f16(w1f[st][ks], b1[ks], c1, 0, 0, 0);
            c2 = __builtin_amdgcn_mfma_f32_16x16x32_f16(w2f[st][ks], b2[ks], c2, 0, 0, 0);
        }
        #pragma unroll
        for (int i = 0; i < 4; ++i) {
            h1c[st][i] = (_Float16)c1[i];
            h2c[st][i] = (_Float16)c2[i];
        }
    }

    // ---- Stage 2 + GEMM2 over 9 p-tiles; Y/Yw frags dbuf'd from ws ----
    f32x4 oacc0 = (f32x4){0.f, 0.f, 0.f, 0.f};
    f32x4 oacc1 = (f32x4){0.f, 0.f, 0.f, 0.f};

    #pragma unroll 1
    for (int pt = 0; pt < 9; ++pt) {
        f16x4 yfn0, yfn1, yw0n, yw1n;
        if (pt < 8) {
            yfn0 = ld4(&wsYf[((pt + 1) * 2 + 0) * 256 + lane * 4]);
            yfn1 = ld4(&wsYf[((pt + 1) * 2 + 1) * 256 + lane * 4]);
            yw0n = ld4(&wsYw[(0 * 9 + pt + 1) * 256 + lane * 4]);
            yw1n = ld4(&wsYw[(1 * 9 + pt + 1) * 256 + lane * 4]);
        }
        const f32x4 z = (f32x4){0.f, 0.f, 0.f, 0.f};
        f32x4 g1 = __builtin_amdgcn_mfma_f32_16x16x16f16(yfc0, h1c[0], z, 0, 0, 0);
        g1       = __builtin_amdgcn_mfma_f32_16x16x16f16(yfc1, h1c[1], g1, 0, 0, 0);
        f32x4 g2 = __builtin_amdgcn_mfma_f32_16x16x16f16(yfc0, h2c[0], z, 0, 0, 0);
        g2       = __builtin_amdgcn_mfma_f32_16x16x16f16(yfc1, h2c[1], g2, 0, 0, 0);
        f16x4 h;
        h[0] = (_Float16)(g1[0] * g2[0]);
        h[1] = (_Float16)(g1[1] * g2[1]);
        h[2] = (_Float16)(g1[2] * g2[2]);
        h[3] = (_Float16)(g1[3] * g2[3]);
        oacc0 = __builtin_amdgcn_mfma_f32_16x16x16f16(yw0c, h, oacc0, 0, 0, 0);
        oacc1 = __builtin_amdgcn_mfma_f32_16x16x16f16(yw1c, h, oacc1, 0, 0, 0);
        yfc0 = yfn0; yfc1 = yfn1; yw0c = yw0n; yw1c = yw1n;
    }

    // ---- stores: out^T C-layout (n=row, m=s) -> 16B runs ----
    float* rp = out + (rowbase + r) * kS;
    *reinterpret_cast<f32x4u*>(rp + quad * 4) = oacc0;
    if (quad < 2) {
        *reinterpret_cast<f32x4u*>(rp + 16 + quad * 4) = oacc1;
    } else if (quad == 2) {
        rp[24] = oacc1[0];
    }
}

extern "C" void kernel_launch(void* const* d_in, const int* in_sizes, int n_in,
                              void* d_out, int out_size, void* d_ws, size_t ws_size,
                              hipStream_t stream) {
    const float* in1 = (const float*)d_in[0];   // [N, 64]
    const float* in2 = (const float*)d_in[1];   // [N, 64]
    const float* W1  = (const float*)d_in[2];   // [64, 25]
    const float* W2  = (const float*)d_in[3];   // [64, 25]
    const float* Y   = (const float*)d_in[4];   // [132, 25]
    const float* Yw  = (const float*)d_in[5];   // [132, 25]
    float* out = (float*)d_out;                 // [N, 25]
    _Float16* ws = (_Float16*)d_ws;             // 13312 halfs used

    precompute11<<<52, 256, 0, stream>>>(W1, W2, Y, Yw, ws);

    const int n_rows = in_sizes[0] / kD;        // 131072
    const int grid = n_rows / kM;               // 2048
    gaunt_fused11<<<grid, kBlock, 0, stream>>>(in1, in2, ws, out);
}

// Round 6
// 108.012 us; speedup vs baseline: 1.0856x; 1.0425x over previous
//
#include <hip/hip_runtime.h>

// GauntTensorProductFixedParity — R12: 4-chunk counted-vmcnt pipeline.
//
// R11 was latency-exposed in two places: per-block vmcnt(0) drain after the
// global_load_lds burst (__syncthreads semantics), and per-pt frag loads in
// the hot loop. R12: 256 rows/block as 4 chunks of 64 rows, double-buffered
// 2x32KB LDS, counted s_waitcnt vmcnt(8) + raw s_barrier (m201 pattern) so
// the next chunk's 8 loads/wave stay in flight across the current chunk's
// compute; ALL operand frags (W/Yf/Yw, 136 VGPR) preloaded to registers and
// the pt-loop fully unrolled -> zero loads in the inner loop; stores
// deferred to the end so vmcnt counts only loads.
// LDS 64KB -> 2 blocks/CU x 4 waves = 8 waves/CU; grid 512 (co-resident).
//
// Compute chain = R9/R11's harness-verified pipeline (math untouched):
//   stage 1 (16x16x32): c^T[s,row]  = sum_d W[d,s]·in[row,d]   (A=Wf, B=in)
//   stage 2 (16x16x16): G[p,row]    = sum_s Y[p,s]·c^T[s,row]  (A=Yf, B=c-chain)
//   H = G1 ⊙ G2 ; GEMM2 (16x16x16): out[s,row] += sum_p Yw^T[s,p]·H[p,row]
// Lane mappings (harness-verified R7-R11):
//   A/B-frag K=32: (idx = lane&15, k = quad*8+j)
//   A/B-frag K=16: (idx = lane&15, k = quad*4+i)
//   C/D:           (n = lane&15,   m = quad*4+i)
// LDS tile 16B-slot XOR swizzle (both-sides rule, verified R11):
// logical (r,s) lives at (r, s ^ (r&7)); source pre-swizzled, dest linear.

typedef _Float16 f16x8 __attribute__((ext_vector_type(8)));
typedef _Float16 f16x4 __attribute__((ext_vector_type(4)));
typedef float f32x4 __attribute__((ext_vector_type(4)));
typedef float f32x4u __attribute__((ext_vector_type(4), aligned(4)));

namespace {
constexpr int kD = 64, kS = 25, kP = 132;
constexpr int kBlock = 256;
constexpr int kCh = 64;                  // rows per chunk (4 waves x 16 rows)
constexpr int kChunks = 4;               // 256 rows per block
// ws layout (halfs):
constexpr int kYfOff = 0;                // Yf  [pt9][st2][64][4] = 4608
constexpr int kYwOff = 4608;             // Ywt [st2][pt9][64][4] = 4608
constexpr int kWfOff = 9216;             // Wf  [op2][st2][ks2][64][8] = 4096
constexpr int kWsHalfs = 13312;          // 26624 B
}

// ---- Precompute: pure-swizzle frag tables (no FMA) ----
__global__ void precompute12(const float* __restrict__ W1,
                             const float* __restrict__ W2,
                             const float* __restrict__ Y,
                             const float* __restrict__ Yw,
                             _Float16* __restrict__ ws) {
    const int e = blockIdx.x * blockDim.x + threadIdx.x;
    if (e < 4608) {
        // Yf(pt,st): A(m = p = pt*16+lo16, k = s = st*16+quad*4+i)
        const int i = e & 3, ln = (e >> 2) & 63, r = e >> 8;   // r 0..17
        const int pt = r >> 1, st = r & 1;
        const int p = pt * 16 + (ln & 15);
        const int s = st * 16 + ((ln >> 4) & 3) * 4 + i;
        ws[kYfOff + e] = (s < kS && p < kP) ? (_Float16)Y[p * kS + s]
                                            : (_Float16)0.f;
    } else if (e < 9216) {
        // Ywt(st,pt): A(m = s = st*16+lo16, k = p = pt*16+quad*4+i)
        const int e2 = e - 4608;
        const int i = e2 & 3, ln = (e2 >> 2) & 63, r = e2 >> 8; // r 0..17
        const int pt = r % 9, st = r / 9;
        const int p = pt * 16 + ((ln >> 4) & 3) * 4 + i;
        const int s = st * 16 + (ln & 15);
        ws[kYwOff + e2] = (s < kS && p < kP) ? (_Float16)Yw[p * kS + s]
                                             : (_Float16)0.f;
    } else if (e < kWsHalfs) {
        // Wf(op,st,ks): A(m = s = st*16+lo16, k = d = ks*32+quad*8+j)
        const int e3 = e - 9216;
        const int j = e3 & 7, ln = (e3 >> 3) & 63, r = e3 >> 9; // r 0..7
        const int ks = r & 1, st = (r >> 1) & 1, op = r >> 2;
        const int s = st * 16 + (ln & 15);
        const int d = ks * 32 + ((ln >> 4) & 3) * 8 + j;
        const float* W = op ? W2 : W1;
        ws[kWfOff + e3] = (s < kS) ? (_Float16)W[d * kS + s] : (_Float16)0.f;
    }
}

__device__ __forceinline__ f16x8 ld8(const _Float16* p) {
    return *reinterpret_cast<const f16x8*>(p);
}
__device__ __forceinline__ f16x4 ld4(const _Float16* p) {
    return *reinterpret_cast<const f16x4*>(p);
}
__device__ __forceinline__ f16x8 cvt8h(f32x4 u, f32x4 v) {
    f16x8 r;
    r[0] = (_Float16)u[0]; r[1] = (_Float16)u[1];
    r[2] = (_Float16)u[2]; r[3] = (_Float16)u[3];
    r[4] = (_Float16)v[0]; r[5] = (_Float16)v[1];
    r[6] = (_Float16)v[2]; r[7] = (_Float16)v[3];
    return r;
}

__global__ __launch_bounds__(kBlock, 2) void gaunt_fused12(
    const float* __restrict__ in1, const float* __restrict__ in2,
    const _Float16* __restrict__ ws, float* __restrict__ out)
{
    // [buf][op][row 64][slot 16] of f32x4, 16-B slots XOR-swizzled. 64 KB.
    __shared__ f32x4 ldsq[2][2][kCh][16];

    const int tid  = threadIdx.x;
    const int lane = tid & 63;
    const int w    = __builtin_amdgcn_readfirstlane(tid >> 6);
    const int lo16 = lane & 15, quad = lane >> 4;
    const long long rowbase = (long long)blockIdx.x * (kChunks * kCh);

    const int rg = lane >> 4;              // row within 4-row group
    const int sl = lane & 15;              // dest slot

    // Stage one 64-row x 2-op chunk into buffer `buf`: 8 global_load_lds(16B)
    // per wave; wave-uniform dest base, per-lane pre-swizzled SOURCE slot.
    auto stage = [&](int chunk, int buf) {
        #pragma unroll
        for (int i = 0; i < 8; ++i) {
            const int t  = w * 8 + i;      // 0..31
            const int op = t >> 4, q = t & 15;
            const int r  = q * 4 + rg;
            const int c16 = sl ^ (r & 7);  // source slot (inverse swizzle)
            const float* src = (op ? in2 : in1)
                + (rowbase + chunk * kCh + r) * kD + c16 * 4;
            char* dst = (char*)(&ldsq[buf][op][q * 4][0]);
            __builtin_amdgcn_global_load_lds(
                (const __attribute__((address_space(1))) void*)src,
                (__attribute__((address_space(3))) void*)dst,
                16, 0, 0);
        }
    };

    // ---- chunk 0 staging first ----
    stage(0, 0);

    // ---- preload ALL operand frags into registers (overlaps c0 latency) ----
    const _Float16* wsYf = ws + kYfOff;
    const _Float16* wsYw = ws + kYwOff;
    const _Float16* wsWf = ws + kWfOff;

    f16x8 wf[2][2][2];                     // [op][st][ks]
    #pragma unroll
    for (int op = 0; op < 2; ++op)
        #pragma unroll
        for (int st = 0; st < 2; ++st)
            #pragma unroll
            for (int ks = 0; ks < 2; ++ks)
                wf[op][st][ks] = ld8(&wsWf[((op * 2 + st) * 2 + ks) * 512 + lane * 8]);

    f16x4 yf[9][2], yw[2][9];
    #pragma unroll
    for (int pt = 0; pt < 9; ++pt) {
        yf[pt][0] = ld4(&wsYf[(pt * 2 + 0) * 256 + lane * 4]);
        yf[pt][1] = ld4(&wsYf[(pt * 2 + 1) * 256 + lane * 4]);
        yw[0][pt] = ld4(&wsYw[(0 * 9 + pt) * 256 + lane * 4]);
        yw[1][pt] = ld4(&wsYw[(1 * 9 + pt) * 256 + lane * 4]);
    }

    // ---- chunk 1 prefetch (stays in flight across chunk 0 compute) ----
    stage(1, 1);

    const int r  = w * 16 + lo16;          // local row this lane consumes
    const int r7 = lo16 & 7;               // (w*16+lo16)&7 == lo16&7

    f32x4 o0[kChunks], o1[kChunks];
    #pragma unroll
    for (int c = 0; c < kChunks; ++c) {
        o0[c] = (f32x4){0.f, 0.f, 0.f, 0.f};
        o1[c] = (f32x4){0.f, 0.f, 0.f, 0.f};
    }

    // Compute one chunk from LDS buffer `buf` into (o0c, o1c). Zero loads in
    // the pt loop: frags are register-resident, loop fully unrolled.
    auto compute = [&](int buf, f32x4& o0c, f32x4& o1c) {
        f16x8 b[2][2];                     // [op][ks]
        #pragma unroll
        for (int op = 0; op < 2; ++op)
            #pragma unroll
            for (int ks = 0; ks < 2; ++ks) {
                const int s0 = ks * 8 + quad * 2;
                const f32x4 u = ldsq[buf][op][r][s0 ^ r7];
                const f32x4 v = ldsq[buf][op][r][(s0 + 1) ^ r7];
                b[op][ks] = cvt8h(u, v);
            }
        f16x4 h1[2], h2[2];                // [st] chain B-frags (n=row, k=s)
        #pragma unroll
        for (int st = 0; st < 2; ++st) {
            f32x4 c1 = (f32x4){0.f, 0.f, 0.f, 0.f};
            f32x4 c2 = (f32x4){0.f, 0.f, 0.f, 0.f};
            #pragma unroll
            for (int ks = 0; ks < 2; ++ks) {
                c1 = __builtin_amdgcn_mfma_f32_16x16x32_f16(wf[0][st][ks], b[0][ks], c1, 0, 0, 0);
                c2 = __builtin_amdgcn_mfma_f32_16x16x32_f16(wf[1][st][ks], b[1][ks], c2, 0, 0, 0);
            }
            #pragma unroll
            for (int i = 0; i < 4; ++i) {
                h1[st][i] = (_Float16)c1[i];
                h2[st][i] = (_Float16)c2[i];
            }
        }
        #pragma unroll
        for (int pt = 0; pt < 9; ++pt) {
            const f32x4 z = (f32x4){0.f, 0.f, 0.f, 0.f};
            f32x4 g1 = __builtin_amdgcn_mfma_f32_16x16x16f16(yf[pt][0], h1[0], z, 0, 0, 0);
            g1       = __builtin_amdgcn_mfma_f32_16x16x16f16(yf[pt][1], h1[1], g1, 0, 0, 0);
            f32x4 g2 = __builtin_amdgcn_mfma_f32_16x16x16f16(yf[pt][0], h2[0], z, 0, 0, 0);
            g2       = __builtin_amdgcn_mfma_f32_16x16x16f16(yf[pt][1], h2[1], g2, 0, 0, 0);
            f16x4 h;
            h[0] = (_Float16)(g1[0] * g2[0]);
            h[1] = (_Float16)(g1[1] * g2[1]);
            h[2] = (_Float16)(g1[2] * g2[2]);
            h[3] = (_Float16)(g1[3] * g2[3]);
            o0c = __builtin_amdgcn_mfma_f32_16x16x16f16(yw[0][pt], h, o0c, 0, 0, 0);
            o1c = __builtin_amdgcn_mfma_f32_16x16x16f16(yw[1][pt], h, o1c, 0, 0, 0);
        }
    };

    // ---- pipelined chunk sequence: counted vmcnt, never drain mid-loop ----
    // waitcnt(8) before each barrier leaves the newest 8 loads (next chunk's
    // prefetch) in flight; per-wave waitcnt + barrier => all waves' loads for
    // the current chunk have landed.
    asm volatile("s_waitcnt vmcnt(8)" ::: "memory");
    __builtin_amdgcn_s_barrier();
    compute(0, o0[0], o1[0]);
    __builtin_amdgcn_s_barrier();          // buf0 free
    stage(2, 0);
    asm volatile("s_waitcnt vmcnt(8)" ::: "memory");
    __builtin_amdgcn_s_barrier();
    compute(1, o0[1], o1[1]);
    __builtin_amdgcn_s_barrier();          // buf1 free
    stage(3, 1);
    asm volatile("s_waitcnt vmcnt(8)" ::: "memory");
    __builtin_amdgcn_s_barrier();
    compute(0, o0[2], o1[2]);
    asm volatile("s_waitcnt vmcnt(0)" ::: "memory");
    __builtin_amdgcn_s_barrier();
    compute(1, o0[3], o1[3]);

    // ---- stores: out^T C-layout (n=row, m=s) -> 16B runs ----
    #pragma unroll
    for (int c = 0; c < kChunks; ++c) {
        const long long row = rowbase + c * kCh + r;
        float* rp = out + row * kS;
        *reinterpret_cast<f32x4u*>(rp + quad * 4) = o0[c];
        if (quad < 2) {
            *reinterpret_cast<f32x4u*>(rp + 16 + quad * 4) = o1[c];
        } else if (quad == 2) {
            rp[24] = o1[c][0];
        }
    }
}

extern "C" void kernel_launch(void* const* d_in, const int* in_sizes, int n_in,
                              void* d_out, int out_size, void* d_ws, size_t ws_size,
                              hipStream_t stream) {
    const float* in1 = (const float*)d_in[0];   // [N, 64]
    const float* in2 = (const float*)d_in[1];   // [N, 64]
    const float* W1  = (const float*)d_in[2];   // [64, 25]
    const float* W2  = (const float*)d_in[3];   // [64, 25]
    const float* Y   = (const float*)d_in[4];   // [132, 25]
    const float* Yw  = (const float*)d_in[5];   // [132, 25]
    float* out = (float*)d_out;                 // [N, 25]
    _Float16* ws = (_Float16*)d_ws;             // 13312 halfs used

    precompute12<<<52, 256, 0, stream>>>(W1, W2, Y, Yw, ws);

    const int n_rows = in_sizes[0] / kD;        // 131072
    const int grid = n_rows / (kChunks * kCh);  // 512 blocks, 2/CU
    gaunt_fused12<<<grid, kBlock, 0, stream>>>(in1, in2, ws, out);
}